// Round 4
// baseline (267.587 us; speedup 1.0000x reference)
//
#include <hip/hip_runtime.h>

// GridEncoder (instant-NGP hash grid) forward, D=3, L=16, C=2, base_res=16,
// per_level_scale=2.0, log2_hashmap=19, align_corners=False.
//
// KEY NUMERICS (R3 theory): the reference output was produced by JAX/XLA,
// and jax lowers jnp.exp2(x) to exp(x * ln2_f32) in f32. fl32(l*ln2f) is
// exact for all l<=15 EXCEPT l=13 and l=15 (product rounds by +/-8*2^-24),
// so after any <=1-ulp expf:
//   exp2(13) = 8192*(1+4*2^-23)  -> scale13 = exp2*16-1 = 131071.0625
//   exp2(15) = 32768*(1-4*2^-23) -> scale15 = 524286.75
// All other levels give exact powers of two. Everything else in the
// reference is plain f32 op-by-op (mul-round then add-round for pos; no
// contraction), which we mirror with __fmul_rn/__fadd_rn.

constexpr int NLEV = 16;
constexpr int BLK  = 256;

__global__ __launch_bounds__(BLK) void grid_encoder_fwd(
    const float* __restrict__ inputs,
    const float2* __restrict__ emb,
    const int* __restrict__ offsets,
    float2* __restrict__ out,
    int total)   // B * NLEV
{
    // XLA-faithful scales (see header): exact 16*2^l - 1 except l=13, l=15.
    const float SCALES[NLEV] = {
        15.f, 31.f, 63.f, 127.f, 255.f, 511.f, 1023.f, 2047.f,
        4095.f, 8191.f, 16383.f, 32767.f, 65535.f,
        131071.0625f,            // l=13 (XLA exp2 quirk)
        262143.f,
        524286.75f               // l=15 (XLA exp2 quirk)
    };

    int t = blockIdx.x * BLK + threadIdx.x;
    if (t >= total) return;
    int b = t >> 4;
    int l = t & 15;

    float x = inputs[(size_t)b * 3 + 0];
    float y = inputs[(size_t)b * 3 + 1];
    float z = inputs[(size_t)b * 3 + 2];

    int off0  = offsets[l];
    int hsize = offsets[l + 1] - off0;
    int res   = 16 << l;                    // dense stride (levels 0..2; exact there)
    float scale = SCALES[l];
    long long r3 = (long long)res * res * res;
    bool use_hash = r3 > (long long)hsize;  // levels 3..15 (ref's res_f^3>hsize agrees)
    uint32_t uh   = (uint32_t)hsize;
    bool     pow2 = (uh & (uh - 1u)) == 0u; // hashed levels: hsize = 2^19

    // pos: mul-round then add-round, exactly as XLA's two elementwise ops
    float px = __fadd_rn(__fmul_rn(x, scale), 0.5f);
    float py = __fadd_rn(__fmul_rn(y, scale), 0.5f);
    float pz = __fadd_rn(__fmul_rn(z, scale), 0.5f);
    float gx = floorf(px), gy = floorf(py), gz = floorf(pz);
    float fx = __fsub_rn(px, gx), fy = __fsub_rn(py, gy), fz = __fsub_rn(pz, gz);
    int pgx = (int)gx, pgy = (int)gy, pgz = (int)gz;
    float omx = __fsub_rn(1.0f, fx), omy = __fsub_rn(1.0f, fy), omz = __fsub_rn(1.0f, fz);

    float r0 = 0.0f, r1 = 0.0f;
    #pragma unroll
    for (int k = 0; k < 8; ++k) {
        const int bx = k & 1, by = (k >> 1) & 1, bz = (k >> 2) & 1;
        int cx = pgx + bx, cy = pgy + by, cz = pgz + bz;
        float w = __fmul_rn(__fmul_rn(bx ? fx : omx, by ? fy : omy), bz ? fz : omz);

        uint32_t idx;
        if (use_hash) {
            uint32_t h = (uint32_t)cx
                       ^ ((uint32_t)cy * 2654435761u)
                       ^ ((uint32_t)cz * 805459861u);
            idx = pow2 ? (h & (uh - 1u)) : (h % uh);
        } else {
            int di = cx + cy * res + cz * res * res;
            idx = (uint32_t)(di % hsize);
        }
        float2 v = emb[(size_t)off0 + (size_t)idx];
        r0 = __fadd_rn(r0, __fmul_rn(w, v.x));
        r1 = __fadd_rn(r1, __fmul_rn(w, v.y));
    }
    out[t] = make_float2(r0, r1);
}

extern "C" void kernel_launch(void* const* d_in, const int* in_sizes, int n_in,
                              void* d_out, int out_size, void* d_ws, size_t ws_size,
                              hipStream_t stream) {
    const float*  inputs  = (const float*)d_in[0];
    const float2* emb     = (const float2*)d_in[1];
    const int*    offsets = (const int*)d_in[2];
    float2*       out     = (float2*)d_out;
    int B = in_sizes[0] / 3;
    int total = B * NLEV;
    int grid = (total + BLK - 1) / BLK;
    hipLaunchKernelGGL(grid_encoder_fwd, dim3(grid), dim3(BLK), 0, stream,
                       inputs, emb, offsets, out, total);
}

// Round 5
// 176.359 us; speedup vs baseline: 1.5173x; 1.5173x over previous
//
#include <hip/hip_runtime.h>

// GridEncoder (instant-NGP hash grid) forward, D=3, L=16, C=2, base_res=16,
// per_level_scale=2.0, log2_hashmap=19, align_corners=False.
//
// NUMERICS (verified R3/R4): reference was produced by JAX/XLA; jnp.exp2(x)
// lowers to exp(x*ln2_f32), so scales are exact 16*2^l-1 EXCEPT
//   l=13 -> 131071.0625, l=15 -> 524286.75.
// pos = mul-round then add-round (no FMA contraction); all weight/accum math
// in plain f32 op-by-op (__fmul_rn/__fadd_rn). Passed with absmax 4.8e-7.
//
// R4 perf change: level-major two-pass. Blocks ordered level-major so each
// XCD's 4MiB L2 holds only the ~2 concurrently-active 4MiB hash tables
// (instead of a 54MB mix) -> compulsory-dominated FETCH. Gather pass writes
// coalesced to ws[l][b]; a streaming transpose produces out[b][l]. Falls
// back to direct strided stores if ws_size < B*16*8 bytes.

constexpr int NLEV = 16;
constexpr int BLK  = 256;

template<bool TO_WS>
__global__ __launch_bounds__(BLK) void grid_gather(
    const float* __restrict__ inputs,
    const float2* __restrict__ emb,
    const int* __restrict__ offsets,
    float2* __restrict__ dst,     // TO_WS: ws layout [l][b]; else out layout [b][l]
    int B, int chunks)
{
    // XLA-faithful scales (see header)
    const float SCALES[NLEV] = {
        15.f, 31.f, 63.f, 127.f, 255.f, 511.f, 1023.f, 2047.f,
        4095.f, 8191.f, 16383.f, 32767.f, 65535.f,
        131071.0625f,            // l=13 (XLA exp2 quirk)
        262143.f,
        524286.75f               // l=15 (XLA exp2 quirk)
    };

    int l = blockIdx.x / chunks;          // level-major: all blocks of a level
    int chunk = blockIdx.x - l * chunks;  // dispatch together
    int b = chunk * BLK + threadIdx.x;
    if (b >= B) return;

    float x = inputs[(size_t)b * 3 + 0];
    float y = inputs[(size_t)b * 3 + 1];
    float z = inputs[(size_t)b * 3 + 2];

    int off0  = offsets[l];
    int hsize = offsets[l + 1] - off0;
    int res   = 16 << l;                    // dense stride (levels 0..2; exact there)
    float scale = SCALES[l];
    long long r3 = (long long)res * res * res;
    bool use_hash = r3 > (long long)hsize;  // levels 3..15
    uint32_t uh   = (uint32_t)hsize;
    bool     pow2 = (uh & (uh - 1u)) == 0u; // hashed levels: hsize = 2^19

    // pos: mul-round then add-round, exactly as XLA's two elementwise ops
    float px = __fadd_rn(__fmul_rn(x, scale), 0.5f);
    float py = __fadd_rn(__fmul_rn(y, scale), 0.5f);
    float pz = __fadd_rn(__fmul_rn(z, scale), 0.5f);
    float gx = floorf(px), gy = floorf(py), gz = floorf(pz);
    float fx = __fsub_rn(px, gx), fy = __fsub_rn(py, gy), fz = __fsub_rn(pz, gz);
    int pgx = (int)gx, pgy = (int)gy, pgz = (int)gz;
    float omx = __fsub_rn(1.0f, fx), omy = __fsub_rn(1.0f, fy), omz = __fsub_rn(1.0f, fz);

    float r0 = 0.0f, r1 = 0.0f;
    #pragma unroll
    for (int k = 0; k < 8; ++k) {
        const int bx = k & 1, by = (k >> 1) & 1, bz = (k >> 2) & 1;
        int cx = pgx + bx, cy = pgy + by, cz = pgz + bz;
        float w = __fmul_rn(__fmul_rn(bx ? fx : omx, by ? fy : omy), bz ? fz : omz);

        uint32_t idx;
        if (use_hash) {
            uint32_t h = (uint32_t)cx
                       ^ ((uint32_t)cy * 2654435761u)
                       ^ ((uint32_t)cz * 805459861u);
            idx = pow2 ? (h & (uh - 1u)) : (h % uh);
        } else {
            int di = cx + cy * res + cz * res * res;
            idx = (uint32_t)(di % hsize);
        }
        float2 v = emb[(size_t)off0 + (size_t)idx];
        r0 = __fadd_rn(r0, __fmul_rn(w, v.x));
        r1 = __fadd_rn(r1, __fmul_rn(w, v.y));
    }

    if (TO_WS)
        dst[(size_t)l * B + b] = make_float2(r0, r1);      // coalesced
    else
        dst[(size_t)b * NLEV + l] = make_float2(r0, r1);   // strided fallback
}

__global__ __launch_bounds__(256) void transpose_out(
    const float2* __restrict__ ws,
    float2* __restrict__ out,
    int B)
{
    int b = blockIdx.x * 256 + threadIdx.x;
    if (b >= B) return;
    float2 v[NLEV];
    #pragma unroll
    for (int l = 0; l < NLEV; ++l)
        v[l] = ws[(size_t)l * B + b];                      // coalesced along lanes
    float4* o = (float4*)(out + (size_t)b * NLEV);         // 128B/point, 16B aligned
    #pragma unroll
    for (int i = 0; i < 8; ++i)
        o[i] = make_float4(v[2*i].x, v[2*i].y, v[2*i+1].x, v[2*i+1].y);
}

extern "C" void kernel_launch(void* const* d_in, const int* in_sizes, int n_in,
                              void* d_out, int out_size, void* d_ws, size_t ws_size,
                              hipStream_t stream) {
    const float*  inputs  = (const float*)d_in[0];
    const float2* emb     = (const float2*)d_in[1];
    const int*    offsets = (const int*)d_in[2];
    float2*       out     = (float2*)d_out;
    int B = in_sizes[0] / 3;
    int chunks = (B + BLK - 1) / BLK;
    int grid = NLEV * chunks;

    bool use_ws = ws_size >= (size_t)B * NLEV * sizeof(float2);
    if (use_ws) {
        float2* ws = (float2*)d_ws;
        hipLaunchKernelGGL((grid_gather<true>), dim3(grid), dim3(BLK), 0, stream,
                           inputs, emb, offsets, ws, B, chunks);
        hipLaunchKernelGGL(transpose_out, dim3((B + 255) / 256), dim3(256), 0, stream,
                           ws, out, B);
    } else {
        hipLaunchKernelGGL((grid_gather<false>), dim3(grid), dim3(BLK), 0, stream,
                           inputs, emb, offsets, out, B, chunks);
    }
}

// Round 6
// 155.635 us; speedup vs baseline: 1.7193x; 1.1332x over previous
//
#include <hip/hip_runtime.h>

// GridEncoder (instant-NGP hash grid) forward, D=3, L=16, C=2, base_res=16,
// per_level_scale=2.0, log2_hashmap=19, align_corners=False.
//
// NUMERICS (verified R3/R4, absmax 4.8e-7): reference is JAX/XLA; jnp.exp2
// lowers to exp(x*ln2_f32) so scales are exact 16*2^l-1 EXCEPT
//   l=13 -> 131071.0625, l=15 -> 524286.75.
// pos = mul-round then add-round (no FMA); weights ((wx*wy)*wz) and the
// k=0..7 accumulation order are kept op-by-op in f32 (__fmul_rn/__fadd_rn).
//
// R5 perf change (gather request reduction): hash primes are (1,p2,p3), so
// for even cx the x-corner pair (cx,cx+1) hashes to an adjacent 16B-aligned
// table pair {2k,2k+1}. Load each corner's pair-line with an unconditional
// float4 at (idx&~1); for even-cx lanes the second load is same-address (L1
// hit, no L2 request) -> hashed-level L2 requests drop 8 -> ~6 per point.
// Branchless, so loads cluster for MLP. Dense levels (0..2) keep plain path.

constexpr int NLEV = 16;
constexpr int BLK  = 256;

template<bool TO_WS>
__global__ __launch_bounds__(BLK) void grid_gather(
    const float* __restrict__ inputs,
    const float2* __restrict__ emb,
    const int* __restrict__ offsets,
    float2* __restrict__ dst,     // TO_WS: ws layout [l][b]; else out layout [b][l]
    int B, int chunks)
{
    // XLA-faithful scales (see header)
    const float SCALES[NLEV] = {
        15.f, 31.f, 63.f, 127.f, 255.f, 511.f, 1023.f, 2047.f,
        4095.f, 8191.f, 16383.f, 32767.f, 65535.f,
        131071.0625f,            // l=13 (XLA exp2 quirk)
        262143.f,
        524286.75f               // l=15 (XLA exp2 quirk)
    };

    int l = blockIdx.x / chunks;          // level-major: all blocks of a level
    int chunk = blockIdx.x - l * chunks;  // dispatch together (L2 locality)
    int b = chunk * BLK + threadIdx.x;
    if (b >= B) return;

    float x = inputs[(size_t)b * 3 + 0];
    float y = inputs[(size_t)b * 3 + 1];
    float z = inputs[(size_t)b * 3 + 2];

    int off0  = offsets[l];
    int hsize = offsets[l + 1] - off0;
    int res   = 16 << l;
    float scale = SCALES[l];
    long long r3 = (long long)res * res * res;
    bool use_hash = r3 > (long long)hsize;  // block-uniform (levels 3..15)
    uint32_t uh   = (uint32_t)hsize;
    bool     pow2 = (uh & (uh - 1u)) == 0u;

    // pos: mul-round then add-round, exactly as XLA's two elementwise ops
    float px = __fadd_rn(__fmul_rn(x, scale), 0.5f);
    float py = __fadd_rn(__fmul_rn(y, scale), 0.5f);
    float pz = __fadd_rn(__fmul_rn(z, scale), 0.5f);
    float gx = floorf(px), gy = floorf(py), gz = floorf(pz);
    float fx = __fsub_rn(px, gx), fy = __fsub_rn(py, gy), fz = __fsub_rn(pz, gz);
    int pgx = (int)gx, pgy = (int)gy, pgz = (int)gz;
    float omx = __fsub_rn(1.0f, fx), omy = __fsub_rn(1.0f, fy), omz = __fsub_rn(1.0f, fz);

    float r0 = 0.0f, r1 = 0.0f;

    if (use_hash && pow2) {
        const uint32_t mask = uh - 1u;
        const float2* tab = emb + (size_t)off0;   // 64B-aligned (off0 % 8 == 0)
        #pragma unroll
        for (int k2 = 0; k2 < 4; ++k2) {
            const int by = k2 & 1, bz = (k2 >> 1) & 1;
            uint32_t m = ((uint32_t)(pgy + by) * 2654435761u)
                       ^ ((uint32_t)(pgz + bz) * 805459861u);
            uint32_t i0 = ((uint32_t)pgx ^ m) & mask;        // corner bx=0
            uint32_t i1 = ((uint32_t)(pgx + 1) ^ m) & mask;  // corner bx=1
            // pair-line loads, 16B aligned; for even pgx both hit one line
            float4 q0 = *(const float4*)(tab + (i0 & ~1u));
            float4 q1 = *(const float4*)(tab + (i1 & ~1u));
            float2 v0 = (i0 & 1u) ? make_float2(q0.z, q0.w) : make_float2(q0.x, q0.y);
            float2 v1 = (i1 & 1u) ? make_float2(q1.z, q1.w) : make_float2(q1.x, q1.y);
            float wy = by ? fy : omy;
            float wz = bz ? fz : omz;
            float w0 = __fmul_rn(__fmul_rn(omx, wy), wz);  // ((wx*wy)*wz) order
            float w1 = __fmul_rn(__fmul_rn(fx,  wy), wz);
            // accumulation order == reference k = 2*k2, 2*k2+1
            r0 = __fadd_rn(r0, __fmul_rn(w0, v0.x));
            r1 = __fadd_rn(r1, __fmul_rn(w0, v0.y));
            r0 = __fadd_rn(r0, __fmul_rn(w1, v1.x));
            r1 = __fadd_rn(r1, __fmul_rn(w1, v1.y));
        }
    } else {
        #pragma unroll
        for (int k = 0; k < 8; ++k) {
            const int bx = k & 1, by = (k >> 1) & 1, bz = (k >> 2) & 1;
            int cx = pgx + bx, cy = pgy + by, cz = pgz + bz;
            float w = __fmul_rn(__fmul_rn(bx ? fx : omx, by ? fy : omy), bz ? fz : omz);
            uint32_t idx;
            if (use_hash) {
                uint32_t h = (uint32_t)cx
                           ^ ((uint32_t)cy * 2654435761u)
                           ^ ((uint32_t)cz * 805459861u);
                idx = h % uh;
            } else {
                int di = cx + cy * res + cz * res * res;
                idx = (uint32_t)(di % hsize);
            }
            float2 v = emb[(size_t)off0 + (size_t)idx];
            r0 = __fadd_rn(r0, __fmul_rn(w, v.x));
            r1 = __fadd_rn(r1, __fmul_rn(w, v.y));
        }
    }

    if (TO_WS)
        dst[(size_t)l * B + b] = make_float2(r0, r1);      // coalesced
    else
        dst[(size_t)b * NLEV + l] = make_float2(r0, r1);   // strided fallback
}

// ws [l][b] (float2) -> out [b][l*2+c], vectorized: 2 points per thread
__global__ __launch_bounds__(256) void transpose_out2(
    const float4* __restrict__ ws4,   // ws viewed as float4: [l][B/2]
    float4* __restrict__ out4,        // out viewed as float4: [B][8]
    int B)
{
    int p = blockIdx.x * 256 + threadIdx.x;   // pair of points (2p, 2p+1)
    int half = B >> 1;                        // B even on this problem
    if (p >= half) return;
    float4 v[NLEV];
    #pragma unroll
    for (int l = 0; l < NLEV; ++l)
        v[l] = ws4[(size_t)l * half + p];     // coalesced 16B/lane
    float4* o0 = out4 + (size_t)(2 * p) * 8;
    #pragma unroll
    for (int i = 0; i < 8; ++i) {
        o0[i]     = make_float4(v[2*i].x, v[2*i].y, v[2*i+1].x, v[2*i+1].y);
        o0[i + 8] = make_float4(v[2*i].z, v[2*i].w, v[2*i+1].z, v[2*i+1].w);
    }
}

__global__ __launch_bounds__(256) void transpose_out1(
    const float2* __restrict__ ws,
    float2* __restrict__ out,
    int B)
{
    int b = blockIdx.x * 256 + threadIdx.x;
    if (b >= B) return;
    float2 v[NLEV];
    #pragma unroll
    for (int l = 0; l < NLEV; ++l)
        v[l] = ws[(size_t)l * B + b];
    float4* o = (float4*)(out + (size_t)b * NLEV);
    #pragma unroll
    for (int i = 0; i < 8; ++i)
        o[i] = make_float4(v[2*i].x, v[2*i].y, v[2*i+1].x, v[2*i+1].y);
}

extern "C" void kernel_launch(void* const* d_in, const int* in_sizes, int n_in,
                              void* d_out, int out_size, void* d_ws, size_t ws_size,
                              hipStream_t stream) {
    const float*  inputs  = (const float*)d_in[0];
    const float2* emb     = (const float2*)d_in[1];
    const int*    offsets = (const int*)d_in[2];
    float2*       out     = (float2*)d_out;
    int B = in_sizes[0] / 3;
    int chunks = (B + BLK - 1) / BLK;
    int grid = NLEV * chunks;

    bool use_ws = ws_size >= (size_t)B * NLEV * sizeof(float2);
    if (use_ws) {
        float2* ws = (float2*)d_ws;
        hipLaunchKernelGGL((grid_gather<true>), dim3(grid), dim3(BLK), 0, stream,
                           inputs, emb, offsets, ws, B, chunks);
        if ((B & 1) == 0) {
            hipLaunchKernelGGL(transpose_out2, dim3((B/2 + 255) / 256), dim3(256), 0, stream,
                               (const float4*)ws, (float4*)out, B);
        } else {
            hipLaunchKernelGGL(transpose_out1, dim3((B + 255) / 256), dim3(256), 0, stream,
                               ws, out, B);
        }
    } else {
        hipLaunchKernelGGL((grid_gather<false>), dim3(grid), dim3(BLK), 0, stream,
                           inputs, emb, offsets, out, B, chunks);
    }
}

// Round 7
// 123.413 us; speedup vs baseline: 2.1682x; 1.2611x over previous
//
#include <hip/hip_runtime.h>

// GridEncoder (instant-NGP hash grid) forward, D=3, L=16, C=2, base_res=16,
// per_level_scale=2.0, log2_hashmap=19, align_corners=False.
//
// NUMERICS (verified R3-R5, absmax 4.8e-7): reference is JAX/XLA; jnp.exp2
// lowers to exp(x*ln2_f32) so scales are exact 16*2^l-1 EXCEPT
//   l=13 -> 131071.0625, l=15 -> 524286.75.
// pos = mul-round then add-round (no FMA); weights ((wx*wy)*wz) and the
// k=0..7 accumulation order kept op-by-op in f32 (__fmul_rn/__fadd_rn).
//
// R5: pair-line float4 gathers (prime[0]==1 => corners (cx,cx+1) for even cx
// share a 16B-aligned table pair) -> ~6 L2 requests/point-level on hashed.
// R6a: XCD-pinned levels. blockIdx%8 -> XCD (measured round-robin, m09/m157).
//   XCD x runs level x (all chunks) then level 15-x, so each 4MiB hash table
//   is fetched into exactly ONE XCD's L2, once, and is sole resident there.
// R6b: LDS transpose: stage 32 points x 16 levels per block, write 4KB
//   contiguous per block (8x fewer write requests than lane-strided stores).

constexpr int NLEV = 16;
constexpr int BLK  = 256;

template<bool TO_WS, bool PINNED>
__global__ __launch_bounds__(BLK) void grid_gather(
    const float* __restrict__ inputs,
    const float2* __restrict__ emb,
    const int* __restrict__ offsets,
    float2* __restrict__ dst,     // TO_WS: ws layout [l][b]; else out layout [b][l]
    int B, int chunks)
{
    // XLA-faithful scales (see header)
    const float SCALES[NLEV] = {
        15.f, 31.f, 63.f, 127.f, 255.f, 511.f, 1023.f, 2047.f,
        4095.f, 8191.f, 16383.f, 32767.f, 65535.f,
        131071.0625f,            // l=13 (XLA exp2 quirk)
        262143.f,
        524286.75f               // l=15 (XLA exp2 quirk)
    };

    int l, chunk;
    if (PINNED) {
        // grid = 16*chunks (divisible by 8). XCD = bid&7 (round-robin dispatch).
        int xcd = blockIdx.x & 7;
        int j   = blockIdx.x >> 3;            // [0, 2*chunks)
        if (j < chunks) { l = xcd;      chunk = j; }
        else            { l = 15 - xcd; chunk = j - chunks; }
    } else {
        l = blockIdx.x / chunks;
        chunk = blockIdx.x - l * chunks;
    }
    int b = chunk * BLK + threadIdx.x;
    if (b >= B) return;

    float x = inputs[(size_t)b * 3 + 0];
    float y = inputs[(size_t)b * 3 + 1];
    float z = inputs[(size_t)b * 3 + 2];

    int off0  = offsets[l];
    int hsize = offsets[l + 1] - off0;
    int res   = 16 << l;
    float scale = SCALES[l];
    long long r3 = (long long)res * res * res;
    bool use_hash = r3 > (long long)hsize;  // block-uniform (levels 3..15)
    uint32_t uh   = (uint32_t)hsize;
    bool     pow2 = (uh & (uh - 1u)) == 0u;

    // pos: mul-round then add-round, exactly as XLA's two elementwise ops
    float px = __fadd_rn(__fmul_rn(x, scale), 0.5f);
    float py = __fadd_rn(__fmul_rn(y, scale), 0.5f);
    float pz = __fadd_rn(__fmul_rn(z, scale), 0.5f);
    float gx = floorf(px), gy = floorf(py), gz = floorf(pz);
    float fx = __fsub_rn(px, gx), fy = __fsub_rn(py, gy), fz = __fsub_rn(pz, gz);
    int pgx = (int)gx, pgy = (int)gy, pgz = (int)gz;
    float omx = __fsub_rn(1.0f, fx), omy = __fsub_rn(1.0f, fy), omz = __fsub_rn(1.0f, fz);

    float r0 = 0.0f, r1 = 0.0f;

    if (use_hash && pow2) {
        const uint32_t mask = uh - 1u;
        const float2* tab = emb + (size_t)off0;   // 64B-aligned (off0 % 8 == 0)
        #pragma unroll
        for (int k2 = 0; k2 < 4; ++k2) {
            const int by = k2 & 1, bz = (k2 >> 1) & 1;
            uint32_t m = ((uint32_t)(pgy + by) * 2654435761u)
                       ^ ((uint32_t)(pgz + bz) * 805459861u);
            uint32_t i0 = ((uint32_t)pgx ^ m) & mask;        // corner bx=0
            uint32_t i1 = ((uint32_t)(pgx + 1) ^ m) & mask;  // corner bx=1
            // pair-line loads, 16B aligned; for even pgx both hit one line
            float4 q0 = *(const float4*)(tab + (i0 & ~1u));
            float4 q1 = *(const float4*)(tab + (i1 & ~1u));
            float2 v0 = (i0 & 1u) ? make_float2(q0.z, q0.w) : make_float2(q0.x, q0.y);
            float2 v1 = (i1 & 1u) ? make_float2(q1.z, q1.w) : make_float2(q1.x, q1.y);
            float wy = by ? fy : omy;
            float wz = bz ? fz : omz;
            float w0 = __fmul_rn(__fmul_rn(omx, wy), wz);  // ((wx*wy)*wz) order
            float w1 = __fmul_rn(__fmul_rn(fx,  wy), wz);
            // accumulation order == reference k = 2*k2, 2*k2+1
            r0 = __fadd_rn(r0, __fmul_rn(w0, v0.x));
            r1 = __fadd_rn(r1, __fmul_rn(w0, v0.y));
            r0 = __fadd_rn(r0, __fmul_rn(w1, v1.x));
            r1 = __fadd_rn(r1, __fmul_rn(w1, v1.y));
        }
    } else {
        #pragma unroll
        for (int k = 0; k < 8; ++k) {
            const int bx = k & 1, by = (k >> 1) & 1, bz = (k >> 2) & 1;
            int cx = pgx + bx, cy = pgy + by, cz = pgz + bz;
            float w = __fmul_rn(__fmul_rn(bx ? fx : omx, by ? fy : omy), bz ? fz : omz);
            uint32_t idx;
            if (use_hash) {
                uint32_t h = (uint32_t)cx
                           ^ ((uint32_t)cy * 2654435761u)
                           ^ ((uint32_t)cz * 805459861u);
                idx = h % uh;
            } else {
                int di = cx + cy * res + cz * res * res;
                idx = (uint32_t)(di % hsize);
            }
            float2 v = emb[(size_t)off0 + (size_t)idx];
            r0 = __fadd_rn(r0, __fmul_rn(w, v.x));
            r1 = __fadd_rn(r1, __fmul_rn(w, v.y));
        }
    }

    if (TO_WS)
        dst[(size_t)l * B + b] = make_float2(r0, r1);      // coalesced
    else
        dst[(size_t)b * NLEV + l] = make_float2(r0, r1);   // strided fallback
}

// ws [l][b] (float2, l-major) -> out [b][l*2+c]; LDS-staged so global writes
// are 4KB contiguous per block (lane i -> consecutive float4).
__global__ __launch_bounds__(256) void transpose_lds(
    const float4* __restrict__ ws4,   // ws viewed as float4: [NLEV][B/2]
    float4* __restrict__ out4,        // out viewed as float4: [B][8]
    int B)
{
    __shared__ float2 lds[32][17];    // +1 pad breaks pow2 bank stride
    int halfB = B >> 1;               // B even
    int b0 = blockIdx.x * 32;         // 32 points per block
    int t = threadIdx.x;

    int l = t >> 4, p = t & 15;       // read: 16 levels x 16 point-pairs
    int gp = (b0 >> 1) + p;
    if (gp < halfB) {
        float4 q = ws4[(size_t)l * halfB + gp];   // 256B contiguous per level
        lds[2 * p][l]     = make_float2(q.x, q.y);
        lds[2 * p + 1][l] = make_float2(q.z, q.w);
    }
    __syncthreads();

    int pt = t >> 3, c = t & 7;       // write: 32 points x 8 float4
    int gb = b0 + pt;
    if (gb < B) {
        float2 a  = lds[pt][2 * c];
        float2 b2 = lds[pt][2 * c + 1];
        out4[(size_t)gb * 8 + c] = make_float4(a.x, a.y, b2.x, b2.y);
    }
}

// fallback (odd B): 1 point/thread, per-lane-contiguous writes
__global__ __launch_bounds__(256) void transpose_out1(
    const float2* __restrict__ ws,
    float2* __restrict__ out,
    int B)
{
    int b = blockIdx.x * 256 + threadIdx.x;
    if (b >= B) return;
    float2 v[NLEV];
    #pragma unroll
    for (int l = 0; l < NLEV; ++l)
        v[l] = ws[(size_t)l * B + b];
    float4* o = (float4*)(out + (size_t)b * NLEV);
    #pragma unroll
    for (int i = 0; i < 8; ++i)
        o[i] = make_float4(v[2*i].x, v[2*i].y, v[2*i+1].x, v[2*i+1].y);
}

extern "C" void kernel_launch(void* const* d_in, const int* in_sizes, int n_in,
                              void* d_out, int out_size, void* d_ws, size_t ws_size,
                              hipStream_t stream) {
    const float*  inputs  = (const float*)d_in[0];
    const float2* emb     = (const float2*)d_in[1];
    const int*    offsets = (const int*)d_in[2];
    float2*       out     = (float2*)d_out;
    int B = in_sizes[0] / 3;
    int chunks = (B + BLK - 1) / BLK;
    int grid = NLEV * chunks;

    bool use_ws = ws_size >= (size_t)B * NLEV * sizeof(float2);
    if (use_ws) {
        float2* ws = (float2*)d_ws;
        hipLaunchKernelGGL((grid_gather<true, true>), dim3(grid), dim3(BLK), 0, stream,
                           inputs, emb, offsets, ws, B, chunks);
        if ((B & 1) == 0) {
            hipLaunchKernelGGL(transpose_lds, dim3((B + 31) / 32), dim3(256), 0, stream,
                               (const float4*)ws, (float4*)out, B);
        } else {
            hipLaunchKernelGGL(transpose_out1, dim3((B + 255) / 256), dim3(256), 0, stream,
                               ws, out, B);
        }
    } else {
        hipLaunchKernelGGL((grid_gather<false, false>), dim3(grid), dim3(BLK), 0, stream,
                           inputs, emb, offsets, out, B, chunks);
    }
}